// Round 10
// baseline (219.089 us; speedup 1.0000x reference)
//
#include <hip/hip_runtime.h>
#include <stdint.h>

typedef unsigned short ushort_t;

#define T_SEQ 2048
#define BATCH 4
#define NHEAD 12
#define CEMB 768
#define HDIM 64
#define C3 2304

// ---------- bf16 helpers (HW convert, RNE) ----------
__device__ __forceinline__ ushort_t f2b_hw(float f) {
  union { __bf16 h; ushort_t u; } p;
  p.h = (__bf16)f;
  return p.u;
}
__device__ __forceinline__ uint32_t pkbf16(float lo, float hi) {
  union { __bf16 h[2]; uint32_t u; } p;
  p.h[0] = (__bf16)lo; p.h[1] = (__bf16)hi;
  return p.u;
}

// ---------- async global->LDS 16B ----------
typedef __attribute__((address_space(3))) unsigned int lds_u32_t;
typedef const __attribute__((address_space(1))) unsigned int glb_u32_t;
__device__ __forceinline__ void async_cp16(const void* g, void* l) {
  __builtin_amdgcn_global_load_lds((glb_u32_t*)g, (lds_u32_t*)l, 16, 0, 0);
}

// ---------- fused prep: cvt x -> bf16; transpose+cvt both weights ----------
__global__ __launch_bounds__(256) void prep_k(const float* __restrict__ x, ushort_t* __restrict__ xb,
                                              const float* __restrict__ wa, ushort_t* __restrict__ wT,
                                              const float* __restrict__ wp, ushort_t* __restrict__ wpT) {
  const int blk = blockIdx.x;
  const int tid = threadIdx.x;
  if (blk < 3072) {
    const int i = blk * 256 + tid;
    float4 a = ((const float4*)x)[2 * i];
    float4 b = ((const float4*)x)[2 * i + 1];
    uint4 v;
    v.x = pkbf16(a.x, a.y); v.y = pkbf16(a.z, a.w);
    v.z = pkbf16(b.x, b.y); v.w = pkbf16(b.z, b.w);
    ((uint4*)xb)[i] = v;
    return;
  }
  __shared__ ushort_t tile[32][33];
  const float* in; ushort_t* out; int R, C, bx, by;
  if (blk < 4800) {
    const int t = blk - 3072;
    in = wa; out = wT; R = CEMB; C = C3;
    bx = t % 72; by = t / 72;
  } else {
    const int t = blk - 4800;
    in = wp; out = wpT; R = CEMB; C = CEMB;
    bx = t % 24; by = t / 24;
  }
  const int tx = tid & 31, ty = tid >> 5;
  const int c0 = bx * 32, r0 = by * 32;
  for (int i = ty; i < 32; i += 8)
    tile[i][tx] = f2b_hw(in[(size_t)(r0 + i) * C + c0 + tx]);
  __syncthreads();
  for (int i = ty; i < 32; i += 8)
    out[(size_t)(c0 + i) * R + r0 + tx] = tile[tx][i];
}

// ---------- MFMA GEMM, BK=32, double-buffered prefetch + LDS SWIZZLE ----------
// r10: the fragment reads As[row*32 + quad*8] (64B rows) were an 8-WAY bank
// conflict (16 lanes/quad -> 2 four-bank sets), the exact pathology fixed in
// attn's Ksm at r0/r6 but never applied here. Arithmetic: conflicted DS
// ~5600 cy per K-step per CU vs ~390 cy/pipe MFMA -> GEMMs were DS-bound at
// ~350 TF. Fix (r6-verified involution, rule #21 both-sides):
//   staging: LDS dest lane-linear; GLOBAL source col = ((tid&3)^((tid>>3)&3))*8
//            (row+64 for the e1 half: (row>>1)&3 unchanged -> same swizzle)
//   reads:   physical chunk = quad ^ ((l15>>1)&3)  (wm,wn,t*16 mult. of 16/32
//            -> (row>>1)&3 == (l15>>1)&3)
// -> every quad-group read covers all 8 four-bank sets 2-way (free, m136).
typedef __bf16 bf16x8 __attribute__((ext_vector_type(8)));
typedef float f32x4 __attribute__((ext_vector_type(4)));

template <bool OUTF, int BM>  // BM = M-tile (128 or 64), N-tile fixed 128
__global__ __launch_bounds__(256) void gemm_bt(const ushort_t* __restrict__ A,
                                               const ushort_t* __restrict__ Bt,
                                               const float* __restrict__ bias,
                                               void* __restrict__ Cv,
                                               int M, int N, int K) {
  constexpr int TM = BM / 32;
  __shared__ ushort_t As[2][BM * 32];
  __shared__ ushort_t Bs[2][128 * 32];
  const int tid = threadIdx.x;
  const int m0 = blockIdx.y * BM, n0 = blockIdx.x * 128;
  const int wid = tid >> 6, lane = tid & 63;
  const int quad = lane >> 4, l15 = lane & 15;
  const int wm = (wid >> 1) * (BM / 2), wn = (wid & 1) * 64;
  f32x4 acc[TM][4] = {};

  const int e0 = tid * 8;               // lane-linear 16B chunks (LDS dest)
  const int r0s = tid >> 2;             // staged row (pane-relative)
  const int csw_src = ((tid & 3) ^ ((tid >> 3) & 3)) << 3;  // swizzled src col
  const int r1s = r0s + 64;             // e1 half (BM=128): same swizzle
  const int e1 = e0 + 2048;

  const int csw = (quad ^ ((l15 >> 1) & 3)) << 3;  // swizzled read chunk

  const int KS = K >> 5;  // K-steps of 32

#define GSTAGE(ks, bf)                                                              \
  {                                                                                 \
    const int kc = (ks) << 5;                                                       \
    async_cp16(&A[(size_t)(m0 + r0s) * K + kc + csw_src], &As[bf][e0]);             \
    if constexpr (BM == 128)                                                        \
      async_cp16(&A[(size_t)(m0 + r1s) * K + kc + csw_src], &As[bf][e1]);           \
    async_cp16(&Bt[(size_t)(n0 + r0s) * K + kc + csw_src], &Bs[bf][e0]);            \
    async_cp16(&Bt[(size_t)(n0 + r1s) * K + kc + csw_src], &Bs[bf][e1]);            \
  }

  GSTAGE(0, 0);
  for (int ks = 0; ks < KS; ks++) {
    const int pb = ks & 1;
    __syncthreads();  // tile ks staged (barrier drains vmcnt)
    if (ks + 1 < KS) GSTAGE(ks + 1, pb ^ 1);
    bf16x8 af[TM], bfr[4];
#pragma unroll
    for (int t = 0; t < TM; t++)
      af[t] = *(const bf16x8*)&As[pb][(wm + t * 16 + l15) * 32 + csw];
#pragma unroll
    for (int t = 0; t < 4; t++)
      bfr[t] = *(const bf16x8*)&Bs[pb][(wn + t * 16 + l15) * 32 + csw];
#pragma unroll
    for (int tm = 0; tm < TM; tm++)
#pragma unroll
      for (int tn = 0; tn < 4; tn++)
        acc[tm][tn] = __builtin_amdgcn_mfma_f32_16x16x32_bf16(af[tm], bfr[tn], acc[tm][tn], 0, 0, 0);
  }
#undef GSTAGE

#pragma unroll
  for (int tm = 0; tm < TM; tm++) {
    const int row = m0 + wm + tm * 16 + quad * 4;
#pragma unroll
    for (int tn = 0; tn < 4; tn++) {
      const int col = n0 + wn + tn * 16 + l15;
      const float bv = bias[col];
#pragma unroll
      for (int rr = 0; rr < 4; rr++) {
        if constexpr (OUTF)
          ((float*)Cv)[(size_t)(row + rr) * N + col] = acc[tm][tn][rr] + bv;
        else
          ((ushort_t*)Cv)[(size_t)(row + rr) * N + col] = f2b_hw(acc[tm][tn][rr] + bv);
      }
    }
  }
}

// ---------- MFMA flash attention (r9, UNCHANGED: 75.0us, conflicts 0) ----------
// 64-q tile per block, 256 threads (4 waves x 16 q). 3-buffer K prefetch
// (depth 2) + counted-vmcnt barriers. P in registers + K=32 PV via
// key-permuted Ksm. Plateau confirmed across 5 structural rewrites.
#define VSTR 64

__device__ __forceinline__ void commit_v(ushort_t* __restrict__ vt, const int* __restrict__ offs,
                                         uint4 pV0, uint4 pV1) {
  union { uint32_t u[4]; uint4 v; } a, c;
  a.v = pV0; c.v = pV1;
#pragma unroll
  for (int j = 0; j < 8; j++) {
    uint32_t pk = __builtin_amdgcn_perm(c.u[j >> 1], a.u[j >> 1],
                                        (j & 1) ? 0x07060302u : 0x05040100u);
    *(uint32_t*)&vt[offs[j]] = pk;
  }
}

__global__ __launch_bounds__(256, 4) void attn_mfma_k(const ushort_t* __restrict__ qkv,
                                                      ushort_t* __restrict__ y) {
  __shared__ ushort_t Ksm[3][2][64 * 32];  // [buf][d-half][keyslot*32] 24576 B
  __shared__ ushort_t Vt[2][64 * VSTR];    // [buf][d][key] swizzled    16384 B

  const int qt = 31 - blockIdx.y;          // big tiles first (LPT)
  const int h = blockIdx.x >> 2, b = blockIdx.x & 3;
  const int tid = threadIdx.x;
  const int w = tid >> 6, lane = tid & 63;
  const int quad = lane >> 4, l15 = lane & 15;
  const int nkt = qt + 1;                  // 64-key tiles
  const int qw = qt * 64 + w * 16;         // wave's first q row

  const int e0 = tid * 8;
  const int p_slot = tid >> 2;
  const int key_true = ((p_slot >> 5) << 5) | (((p_slot >> 2) & 3) << 3) |
                       (((p_slot >> 4) & 1) << 2) | (p_slot & 3);
  const int kchunk = (tid & 3) ^ ((p_slot >> 1) & 3);
  const ushort_t* kbase = qkv + ((size_t)(b * T_SEQ) + key_true) * C3 + CEMB + h * HDIM + kchunk * 8;
  const int vpair = tid & 31, vd0 = (tid >> 5) * 8;
  const ushort_t* vbase = qkv + ((size_t)(b * T_SEQ) + 2 * vpair) * C3 + 2 * CEMB + h * HDIM + vd0;
  const size_t step = (size_t)64 * C3;

  int voffw[8];
#pragma unroll
  for (int j = 0; j < 8; j++)
    voffw[j] = (vd0 + j) * VSTR + (((vpair >> 2) ^ j) << 3) + ((vpair & 3) << 1);

  const int sw7 = l15 & 7;
  int koff[4];
#pragma unroll
  for (int m = 0; m < 4; m++)
    koff[m] = (m * 16 + l15) * 32 + ((quad ^ ((l15 >> 1) & 3)) << 3);
  int vroff[2][4];
#pragma unroll
  for (int a2 = 0; a2 < 2; a2++)
#pragma unroll
    for (int nd = 0; nd < 4; nd++)
      vroff[a2][nd] = (nd * 16 + l15) * VSTR + (((4 * a2 + quad) ^ sw7) << 3);

  const int qrel = w * 16 + l15;  // block-relative q row (for mask)

  const float C2 = 0.18033688011112042f;  // 0.125 * log2(e)

  bf16x8 qB[2];
#pragma unroll
  for (int kb = 0; kb < 2; kb++)
    qB[kb] = *(const bf16x8*)&qkv[((size_t)(b * T_SEQ + qw + l15)) * C3 +
                                  h * HDIM + kb * 32 + quad * 8];

  f32x4 o2[4] = {};
  float m0 = -3e38f;
  float lq0 = 0.f;

  // ---- prologue: V0 regs; issue K0,K1; commit V0; load V1 regs ----
  const ushort_t* kp = kbase;
  const ushort_t* vp = vbase;
  uint4 pV0 = *(const uint4*)vp, pV1 = *(const uint4*)(vp + C3);
  async_cp16(kp, &Ksm[0][0][e0]);
  async_cp16(kp + 32, &Ksm[0][1][e0]);
  if (nkt > 1) {
    kp += step;
    async_cp16(kp, &Ksm[1][0][e0]);
    async_cp16(kp + 32, &Ksm[1][1][e0]);
  }
  commit_v(Vt[0], voffw, pV0, pV1);
  if (nkt > 1) {
    vp += step;
    pV0 = *(const uint4*)vp; pV1 = *(const uint4*)(vp + C3);
  }
  if (nkt > 1)
    asm volatile("s_waitcnt vmcnt(2) lgkmcnt(0)\n\ts_barrier" ::: "memory");
  else
    asm volatile("s_waitcnt vmcnt(0) lgkmcnt(0)\n\ts_barrier" ::: "memory");

  int cbk = 0;  // kt % 3
  for (int kt = 0; kt < nkt; ++kt) {
    // ---- issue K(kt+2) into the 3rd buffer (2 iters to land) ----
    if (kt + 2 < nkt) {
      kp += step;
      const int nb = (cbk + 2 >= 3) ? cbk - 1 : cbk + 2;
      async_cp16(kp, &Ksm[nb][0][e0]);
      async_cp16(kp + 32, &Ksm[nb][1][e0]);
    }
    // ---- commit V(kt+1); load V(kt+2) regs ----
    if (kt + 1 < nkt) {
      commit_v(Vt[(kt + 1) & 1], voffw, pV0, pV1);
      if (kt + 2 < nkt) {
        vp += step;
        pV0 = *(const uint4*)vp; pV1 = *(const uint4*)(vp + C3);
      }
    }

    // ---- S^T = K*Q^T ----
    bf16x8 kA[4][2];
#pragma unroll
    for (int m = 0; m < 4; m++) {
      kA[m][0] = *(const bf16x8*)&Ksm[cbk][0][koff[m]];
      kA[m][1] = *(const bf16x8*)&Ksm[cbk][1][koff[m]];
    }
    f32x4 st0[4] = {};
#pragma unroll
    for (int m = 0; m < 4; m++) {
      st0[m] = __builtin_amdgcn_mfma_f32_16x16x32_bf16(kA[m][0], qB[0], st0[m], 0, 0, 0);
      st0[m] = __builtin_amdgcn_mfma_f32_16x16x32_bf16(kA[m][1], qB[1], st0[m], 0, 0, 0);
    }

    // ---- causal mask (permuted keys): diagonal tile only ----
    if (kt == nkt - 1) {
      const int kb0 = quad * 8;
#pragma unroll
      for (int m = 0; m < 4; m++) {
        const int bm = kb0 + ((m >> 1) << 5) + ((m & 1) << 2);
#pragma unroll
        for (int r = 0; r < 4; r++)
          if (bm + r > qrel) st0[m][r] = -3e38f;
      }
    }

    // ---- online softmax: defer-max (T13) ----
    f32x4 mq0;
#pragma unroll
    for (int r = 0; r < 4; r++)
      mq0[r] = fmaxf(fmaxf(st0[0][r], st0[1][r]), fmaxf(st0[2][r], st0[3][r]));
    const float mx0 = fmaxf(fmaxf(mq0[0], mq0[1]), fmaxf(mq0[2], mq0[3]));

    float al0 = 1.f;
    if (__any(mx0 - m0 > 22.18f)) {
      float a = fmaxf(mx0, __shfl_xor(mx0, 16, 64));
      a = fmaxf(a, __shfl_xor(a, 32, 64));
      const float n0 = fmaxf(m0, a);
      al0 = exp2f((m0 - n0) * C2);
      m0 = n0;
#pragma unroll
      for (int nd = 0; nd < 4; nd++)
#pragma unroll
        for (int r = 0; r < 4; r++) o2[nd][r] *= al0;
    }
    const float mnc0 = m0 * C2;
#pragma unroll
    for (int m = 0; m < 4; m++)
#pragma unroll
      for (int r = 0; r < 4; r++)
        st0[m][r] = exp2f(fmaf(st0[m][r], C2, -mnc0));
    f32x4 s40;
#pragma unroll
    for (int r = 0; r < 4; r++)
      s40[r] = (st0[0][r] + st0[1][r]) + (st0[2][r] + st0[3][r]);
    lq0 = fmaf(lq0, al0, (s40[0] + s40[1]) + (s40[2] + s40[3]));

    // ---- P -> 16x16x32 B-fragments in registers ----
    bf16x8 pf0[2];
#pragma unroll
    for (int a2 = 0; a2 < 2; a2++) {
      union { uint32_t u[4]; bf16x8 v; } pa;
      pa.u[0] = pkbf16(st0[2 * a2][0], st0[2 * a2][1]);
      pa.u[1] = pkbf16(st0[2 * a2][2], st0[2 * a2][3]);
      pa.u[2] = pkbf16(st0[2 * a2 + 1][0], st0[2 * a2 + 1][1]);
      pa.u[3] = pkbf16(st0[2 * a2 + 1][2], st0[2 * a2 + 1][3]);
      pf0[a2] = pa.v;
    }

    // ---- O^T += V^T * P^T  (16x16x32) ----
#pragma unroll
    for (int a2 = 0; a2 < 2; a2++)
#pragma unroll
      for (int nd = 0; nd < 4; nd++) {
        const bf16x8 vv = *(const bf16x8*)&Vt[kt & 1][vroff[a2][nd]];
        o2[nd] = __builtin_amdgcn_mfma_f32_16x16x32_bf16(vv, pf0[a2], o2[nd], 0, 0, 0);
      }

    // ---- counted-vmcnt barrier: keep the kt+2 prefetches in flight ----
    if (kt + 2 < nkt)
      asm volatile("s_waitcnt vmcnt(4) lgkmcnt(0)\n\ts_barrier" ::: "memory");
    else if (kt + 1 < nkt)
      asm volatile("s_waitcnt vmcnt(0) lgkmcnt(0)\n\ts_barrier" ::: "memory");
    cbk = (cbk == 2) ? 0 : cbk + 1;
  }

  // ---- epilogue: cross-quad l reduce (deferred), then y stores ----
  {
    float lt0 = lq0 + __shfl_xor(lq0, 16, 64);
    lt0 += __shfl_xor(lt0, 32, 64);
    const float inv = 1.0f / lt0;
    const int qg = qw + l15;
    ushort_t* yp = y + ((size_t)(b * T_SEQ + qg)) * CEMB + h * HDIM + quad * 4;
#pragma unroll
    for (int nd = 0; nd < 4; nd++) {
      uint2 pk;
      pk.x = pkbf16(o2[nd][0] * inv, o2[nd][1] * inv);
      pk.y = pkbf16(o2[nd][2] * inv, o2[nd][3] * inv);
      *(uint2*)(yp + nd * 16) = pk;
    }
  }
}

// ---------- launcher ----------
extern "C" void kernel_launch(void* const* d_in, const int* in_sizes, int n_in,
                              void* d_out, int out_size, void* d_ws, size_t ws_size,
                              hipStream_t stream) {
  const float* x      = (const float*)d_in[0];  // [4,2048,768] fp32
  const float* w_attn = (const float*)d_in[1];  // [768,2304]
  const float* b_attn = (const float*)d_in[2];  // [2304]
  const float* w_proj = (const float*)d_in[3];  // [768,768]
  const float* b_proj = (const float*)d_in[4];  // [768]
  float* out = (float*)d_out;                   // [4,2048,768] fp32

  char* ws = (char*)d_ws;
  ushort_t* qkv = (ushort_t*)ws;                          // 8192*2304 bf16
  ushort_t* y   = qkv + (size_t)8192 * 2304;              // 8192*768
  ushort_t* xb  = y + (size_t)8192 * 768;                 // 8192*768 bf16 x
  ushort_t* wT  = xb + (size_t)8192 * 768;                // 2304*768 (w_attn^T)
  ushort_t* wpT = wT + (size_t)2304 * 768;                // 768*768  (w_proj^T)

  // fused prep: cvt x + transpose both weights
  prep_k<<<5376, 256, 0, stream>>>(x, xb, w_attn, wT, w_proj, wpT);

  // qkv = x @ w_attn + b_attn   (M=8192, N=2304, K=768), bf16 out
  gemm_bt<false, 128><<<dim3(C3 / 128, 8192 / 128), 256, 0, stream>>>(xb, wT, b_attn, qkv, 8192, C3, CEMB);

  // MFMA flash attention -> y [B,T,C] bf16; 64-q blocks, 256 thr, big-first
  attn_mfma_k<<<dim3(48, 32), 256, 0, stream>>>(qkv, y);

  // out = y @ w_proj + b_proj   (M=8192, N=768, K=768), fp32 out
  gemm_bt<true, 64><<<dim3(CEMB / 128, 8192 / 64), 256, 0, stream>>>(y, wpT, b_proj, out, 8192, CEMB, CEMB);
}

// Round 11
// 215.512 us; speedup vs baseline: 1.0166x; 1.0166x over previous
//
#include <hip/hip_runtime.h>
#include <stdint.h>

typedef unsigned short ushort_t;

#define T_SEQ 2048
#define BATCH 4
#define NHEAD 12
#define CEMB 768
#define HDIM 64
#define C3 2304

// ---------- bf16 helpers (HW convert, RNE) ----------
__device__ __forceinline__ ushort_t f2b_hw(float f) {
  union { __bf16 h; ushort_t u; } p;
  p.h = (__bf16)f;
  return p.u;
}
__device__ __forceinline__ uint32_t pkbf16(float lo, float hi) {
  union { __bf16 h[2]; uint32_t u; } p;
  p.h[0] = (__bf16)lo; p.h[1] = (__bf16)hi;
  return p.u;
}

// ---------- async global->LDS 16B ----------
typedef __attribute__((address_space(3))) unsigned int lds_u32_t;
typedef const __attribute__((address_space(1))) unsigned int glb_u32_t;
__device__ __forceinline__ void async_cp16(const void* g, void* l) {
  __builtin_amdgcn_global_load_lds((glb_u32_t*)g, (lds_u32_t*)l, 16, 0, 0);
}

// ---------- fused prep: cvt x -> bf16; transpose+cvt both weights ----------
__global__ __launch_bounds__(256) void prep_k(const float* __restrict__ x, ushort_t* __restrict__ xb,
                                              const float* __restrict__ wa, ushort_t* __restrict__ wT,
                                              const float* __restrict__ wp, ushort_t* __restrict__ wpT) {
  const int blk = blockIdx.x;
  const int tid = threadIdx.x;
  if (blk < 3072) {
    const int i = blk * 256 + tid;
    float4 a = ((const float4*)x)[2 * i];
    float4 b = ((const float4*)x)[2 * i + 1];
    uint4 v;
    v.x = pkbf16(a.x, a.y); v.y = pkbf16(a.z, a.w);
    v.z = pkbf16(b.x, b.y); v.w = pkbf16(b.z, b.w);
    ((uint4*)xb)[i] = v;
    return;
  }
  __shared__ ushort_t tile[32][33];
  const float* in; ushort_t* out; int R, C, bx, by;
  if (blk < 4800) {
    const int t = blk - 3072;
    in = wa; out = wT; R = CEMB; C = C3;
    bx = t % 72; by = t / 72;
  } else {
    const int t = blk - 4800;
    in = wp; out = wpT; R = CEMB; C = CEMB;
    bx = t % 24; by = t / 24;
  }
  const int tx = tid & 31, ty = tid >> 5;
  const int c0 = bx * 32, r0 = by * 32;
  for (int i = ty; i < 32; i += 8)
    tile[i][tx] = f2b_hw(in[(size_t)(r0 + i) * C + c0 + tx]);
  __syncthreads();
  for (int i = ty; i < 32; i += 8)
    out[(size_t)(c0 + i) * R + r0 + tx] = tile[tx][i];
}

// ---------- MFMA GEMM: BK=32, 3-buffer depth-2 prefetch, counted vmcnt ----------
// r11: GEMMs were invariant (~300 TF) across r6/r10 knobs -- same plateau
// signature as attn. The drain-everything barrier (__syncthreads ->
// vmcnt(0)) exposes full load latency each K-step; r9's counted-vmcnt failed
// in attn ONLY because commit_v's register loads force a FIFO drain (found
// confound). The GEMM is a pure global_load_lds stream -> true AITER-style
// pipeline is possible:
//   - 3 LDS buffers; stage(ks+2) issued in iter ks (2 iters to land)
//   - barrier = s_waitcnt vmcnt(VM_N) lgkmcnt(0); s_barrier  -- the newest
//     stage's VM_N loads stay in flight across EVERY barrier (never 0 in
//     steady state); FIFO vmcnt guarantees compute buffer landed; lgkmcnt(0)
//     closes the WAR hazard on the buffer being overwritten next.
// Plus T1 XCD swizzle (1D grid, swz=(bid%8)*(nwg/8)+bid/8, nwg%8==0):
// A-panel-sharing blocks colocate on one XCD L2 (A traffic ~8x down).
// LDS read/stage swizzle from r10 retained (conflict-free, verified).
typedef __bf16 bf16x8 __attribute__((ext_vector_type(8)));
typedef float f32x4 __attribute__((ext_vector_type(4)));

template <bool OUTF, int BM>  // BM = M-tile (128 or 64), N-tile fixed 128
__global__ __launch_bounds__(256) void gemm_bt(const ushort_t* __restrict__ A,
                                               const ushort_t* __restrict__ Bt,
                                               const float* __restrict__ bias,
                                               void* __restrict__ Cv,
                                               int M, int N, int K, int NBX) {
  constexpr int TM = BM / 32;
  __shared__ ushort_t As[3][BM * 32];
  __shared__ ushort_t Bs[3][128 * 32];
  const int tid = threadIdx.x;

  // XCD-aware swizzle (T1): nwg % 8 == 0 (1152 / 768)
  const int nwg = gridDim.x;
  const int bid = blockIdx.x;
  const int swz = (bid & 7) * (nwg >> 3) + (bid >> 3);
  const int bx = swz % NBX, by = swz / NBX;
  const int m0 = by * BM, n0 = bx * 128;

  const int wid = tid >> 6, lane = tid & 63;
  const int quad = lane >> 4, l15 = lane & 15;
  const int wm = (wid >> 1) * (BM / 2), wn = (wid & 1) * 64;
  f32x4 acc[TM][4] = {};

  const int e0 = tid * 8;               // lane-linear 16B chunks (LDS dest)
  const int r0s = tid >> 2;             // staged row (pane-relative)
  const int csw_src = ((tid & 3) ^ ((tid >> 3) & 3)) << 3;  // swizzled src col
  const int r1s = r0s + 64;             // e1 half (BM=128): same swizzle
  const int e1 = e0 + 2048;

  const int csw = (quad ^ ((l15 >> 1) & 3)) << 3;  // swizzled read chunk

  const int KS = K >> 5;  // K-steps of 32

#define GSTAGE(ks, bf)                                                              \
  {                                                                                 \
    const int kc = (ks) << 5;                                                       \
    async_cp16(&A[(size_t)(m0 + r0s) * K + kc + csw_src], &As[bf][e0]);             \
    if constexpr (BM == 128)                                                        \
      async_cp16(&A[(size_t)(m0 + r1s) * K + kc + csw_src], &As[bf][e1]);           \
    async_cp16(&Bt[(size_t)(n0 + r0s) * K + kc + csw_src], &Bs[bf][e0]);            \
    async_cp16(&Bt[(size_t)(n0 + r1s) * K + kc + csw_src], &Bs[bf][e1]);            \
  }

  // prologue: two stages in flight
  GSTAGE(0, 0);
  GSTAGE(1, 1);

  int pb = 0;       // ks % 3 (compute buffer)
  int bstage = 2;   // (ks+2) % 3 (stage buffer)
  for (int ks = 0; ks < KS; ks++) {
    // counted barrier: keep newest stage (VM_N loads) in flight; drain older.
    if (ks + 1 < KS) {
      if constexpr (BM == 128)
        asm volatile("s_waitcnt vmcnt(4) lgkmcnt(0)\n\ts_barrier" ::: "memory");
      else
        asm volatile("s_waitcnt vmcnt(3) lgkmcnt(0)\n\ts_barrier" ::: "memory");
    } else {
      asm volatile("s_waitcnt vmcnt(0) lgkmcnt(0)\n\ts_barrier" ::: "memory");
    }
    if (ks + 2 < KS) GSTAGE(ks + 2, bstage);

    bf16x8 af[TM], bfr[4];
#pragma unroll
    for (int t = 0; t < TM; t++)
      af[t] = *(const bf16x8*)&As[pb][(wm + t * 16 + l15) * 32 + csw];
#pragma unroll
    for (int t = 0; t < 4; t++)
      bfr[t] = *(const bf16x8*)&Bs[pb][(wn + t * 16 + l15) * 32 + csw];
#pragma unroll
    for (int tm = 0; tm < TM; tm++)
#pragma unroll
      for (int tn = 0; tn < 4; tn++)
        acc[tm][tn] = __builtin_amdgcn_mfma_f32_16x16x32_bf16(af[tm], bfr[tn], acc[tm][tn], 0, 0, 0);

    pb = (pb == 2) ? 0 : pb + 1;
    bstage = (bstage == 2) ? 0 : bstage + 1;
  }
#undef GSTAGE

#pragma unroll
  for (int tm = 0; tm < TM; tm++) {
    const int row = m0 + wm + tm * 16 + quad * 4;
#pragma unroll
    for (int tn = 0; tn < 4; tn++) {
      const int col = n0 + wn + tn * 16 + l15;
      const float bv = bias[col];
#pragma unroll
      for (int rr = 0; rr < 4; rr++) {
        if constexpr (OUTF)
          ((float*)Cv)[(size_t)(row + rr) * N + col] = acc[tm][tn][rr] + bv;
        else
          ((ushort_t*)Cv)[(size_t)(row + rr) * N + col] = f2b_hw(acc[tm][tn][rr] + bv);
      }
    }
  }
}

// ---------- MFMA flash attention (r9, UNCHANGED: 75.0us, conflicts 0) ----------
// 64-q tile per block, 256 threads (4 waves x 16 q). 3-buffer K prefetch
// (depth 2) + counted-vmcnt barriers. P in registers + K=32 PV via
// key-permuted Ksm. Plateau confirmed across 5 structural rewrites.
#define VSTR 64

__device__ __forceinline__ void commit_v(ushort_t* __restrict__ vt, const int* __restrict__ offs,
                                         uint4 pV0, uint4 pV1) {
  union { uint32_t u[4]; uint4 v; } a, c;
  a.v = pV0; c.v = pV1;
#pragma unroll
  for (int j = 0; j < 8; j++) {
    uint32_t pk = __builtin_amdgcn_perm(c.u[j >> 1], a.u[j >> 1],
                                        (j & 1) ? 0x07060302u : 0x05040100u);
    *(uint32_t*)&vt[offs[j]] = pk;
  }
}

__global__ __launch_bounds__(256, 4) void attn_mfma_k(const ushort_t* __restrict__ qkv,
                                                      ushort_t* __restrict__ y) {
  __shared__ ushort_t Ksm[3][2][64 * 32];  // [buf][d-half][keyslot*32] 24576 B
  __shared__ ushort_t Vt[2][64 * VSTR];    // [buf][d][key] swizzled    16384 B

  const int qt = 31 - blockIdx.y;          // big tiles first (LPT)
  const int h = blockIdx.x >> 2, b = blockIdx.x & 3;
  const int tid = threadIdx.x;
  const int w = tid >> 6, lane = tid & 63;
  const int quad = lane >> 4, l15 = lane & 15;
  const int nkt = qt + 1;                  // 64-key tiles
  const int qw = qt * 64 + w * 16;         // wave's first q row

  const int e0 = tid * 8;
  const int p_slot = tid >> 2;
  const int key_true = ((p_slot >> 5) << 5) | (((p_slot >> 2) & 3) << 3) |
                       (((p_slot >> 4) & 1) << 2) | (p_slot & 3);
  const int kchunk = (tid & 3) ^ ((p_slot >> 1) & 3);
  const ushort_t* kbase = qkv + ((size_t)(b * T_SEQ) + key_true) * C3 + CEMB + h * HDIM + kchunk * 8;
  const int vpair = tid & 31, vd0 = (tid >> 5) * 8;
  const ushort_t* vbase = qkv + ((size_t)(b * T_SEQ) + 2 * vpair) * C3 + 2 * CEMB + h * HDIM + vd0;
  const size_t step = (size_t)64 * C3;

  int voffw[8];
#pragma unroll
  for (int j = 0; j < 8; j++)
    voffw[j] = (vd0 + j) * VSTR + (((vpair >> 2) ^ j) << 3) + ((vpair & 3) << 1);

  const int sw7 = l15 & 7;
  int koff[4];
#pragma unroll
  for (int m = 0; m < 4; m++)
    koff[m] = (m * 16 + l15) * 32 + ((quad ^ ((l15 >> 1) & 3)) << 3);
  int vroff[2][4];
#pragma unroll
  for (int a2 = 0; a2 < 2; a2++)
#pragma unroll
    for (int nd = 0; nd < 4; nd++)
      vroff[a2][nd] = (nd * 16 + l15) * VSTR + (((4 * a2 + quad) ^ sw7) << 3);

  const int qrel = w * 16 + l15;  // block-relative q row (for mask)

  const float C2 = 0.18033688011112042f;  // 0.125 * log2(e)

  bf16x8 qB[2];
#pragma unroll
  for (int kb = 0; kb < 2; kb++)
    qB[kb] = *(const bf16x8*)&qkv[((size_t)(b * T_SEQ + qw + l15)) * C3 +
                                  h * HDIM + kb * 32 + quad * 8];

  f32x4 o2[4] = {};
  float m0 = -3e38f;
  float lq0 = 0.f;

  // ---- prologue: V0 regs; issue K0,K1; commit V0; load V1 regs ----
  const ushort_t* kp = kbase;
  const ushort_t* vp = vbase;
  uint4 pV0 = *(const uint4*)vp, pV1 = *(const uint4*)(vp + C3);
  async_cp16(kp, &Ksm[0][0][e0]);
  async_cp16(kp + 32, &Ksm[0][1][e0]);
  if (nkt > 1) {
    kp += step;
    async_cp16(kp, &Ksm[1][0][e0]);
    async_cp16(kp + 32, &Ksm[1][1][e0]);
  }
  commit_v(Vt[0], voffw, pV0, pV1);
  if (nkt > 1) {
    vp += step;
    pV0 = *(const uint4*)vp; pV1 = *(const uint4*)(vp + C3);
  }
  if (nkt > 1)
    asm volatile("s_waitcnt vmcnt(2) lgkmcnt(0)\n\ts_barrier" ::: "memory");
  else
    asm volatile("s_waitcnt vmcnt(0) lgkmcnt(0)\n\ts_barrier" ::: "memory");

  int cbk = 0;  // kt % 3
  for (int kt = 0; kt < nkt; ++kt) {
    // ---- issue K(kt+2) into the 3rd buffer (2 iters to land) ----
    if (kt + 2 < nkt) {
      kp += step;
      const int nb = (cbk + 2 >= 3) ? cbk - 1 : cbk + 2;
      async_cp16(kp, &Ksm[nb][0][e0]);
      async_cp16(kp + 32, &Ksm[nb][1][e0]);
    }
    // ---- commit V(kt+1); load V(kt+2) regs ----
    if (kt + 1 < nkt) {
      commit_v(Vt[(kt + 1) & 1], voffw, pV0, pV1);
      if (kt + 2 < nkt) {
        vp += step;
        pV0 = *(const uint4*)vp; pV1 = *(const uint4*)(vp + C3);
      }
    }

    // ---- S^T = K*Q^T ----
    bf16x8 kA[4][2];
#pragma unroll
    for (int m = 0; m < 4; m++) {
      kA[m][0] = *(const bf16x8*)&Ksm[cbk][0][koff[m]];
      kA[m][1] = *(const bf16x8*)&Ksm[cbk][1][koff[m]];
    }
    f32x4 st0[4] = {};
#pragma unroll
    for (int m = 0; m < 4; m++) {
      st0[m] = __builtin_amdgcn_mfma_f32_16x16x32_bf16(kA[m][0], qB[0], st0[m], 0, 0, 0);
      st0[m] = __builtin_amdgcn_mfma_f32_16x16x32_bf16(kA[m][1], qB[1], st0[m], 0, 0, 0);
    }

    // ---- causal mask (permuted keys): diagonal tile only ----
    if (kt == nkt - 1) {
      const int kb0 = quad * 8;
#pragma unroll
      for (int m = 0; m < 4; m++) {
        const int bm = kb0 + ((m >> 1) << 5) + ((m & 1) << 2);
#pragma unroll
        for (int r = 0; r < 4; r++)
          if (bm + r > qrel) st0[m][r] = -3e38f;
      }
    }

    // ---- online softmax: defer-max (T13) ----
    f32x4 mq0;
#pragma unroll
    for (int r = 0; r < 4; r++)
      mq0[r] = fmaxf(fmaxf(st0[0][r], st0[1][r]), fmaxf(st0[2][r], st0[3][r]));
    const float mx0 = fmaxf(fmaxf(mq0[0], mq0[1]), fmaxf(mq0[2], mq0[3]));

    float al0 = 1.f;
    if (__any(mx0 - m0 > 22.18f)) {
      float a = fmaxf(mx0, __shfl_xor(mx0, 16, 64));
      a = fmaxf(a, __shfl_xor(a, 32, 64));
      const float n0 = fmaxf(m0, a);
      al0 = exp2f((m0 - n0) * C2);
      m0 = n0;
#pragma unroll
      for (int nd = 0; nd < 4; nd++)
#pragma unroll
        for (int r = 0; r < 4; r++) o2[nd][r] *= al0;
    }
    const float mnc0 = m0 * C2;
#pragma unroll
    for (int m = 0; m < 4; m++)
#pragma unroll
      for (int r = 0; r < 4; r++)
        st0[m][r] = exp2f(fmaf(st0[m][r], C2, -mnc0));
    f32x4 s40;
#pragma unroll
    for (int r = 0; r < 4; r++)
      s40[r] = (st0[0][r] + st0[1][r]) + (st0[2][r] + st0[3][r]);
    lq0 = fmaf(lq0, al0, (s40[0] + s40[1]) + (s40[2] + s40[3]));

    // ---- P -> 16x16x32 B-fragments in registers ----
    bf16x8 pf0[2];
#pragma unroll
    for (int a2 = 0; a2 < 2; a2++) {
      union { uint32_t u[4]; bf16x8 v; } pa;
      pa.u[0] = pkbf16(st0[2 * a2][0], st0[2 * a2][1]);
      pa.u[1] = pkbf16(st0[2 * a2][2], st0[2 * a2][3]);
      pa.u[2] = pkbf16(st0[2 * a2 + 1][0], st0[2 * a2 + 1][1]);
      pa.u[3] = pkbf16(st0[2 * a2 + 1][2], st0[2 * a2 + 1][3]);
      pf0[a2] = pa.v;
    }

    // ---- O^T += V^T * P^T  (16x16x32) ----
#pragma unroll
    for (int a2 = 0; a2 < 2; a2++)
#pragma unroll
      for (int nd = 0; nd < 4; nd++) {
        const bf16x8 vv = *(const bf16x8*)&Vt[kt & 1][vroff[a2][nd]];
        o2[nd] = __builtin_amdgcn_mfma_f32_16x16x32_bf16(vv, pf0[a2], o2[nd], 0, 0, 0);
      }

    // ---- counted-vmcnt barrier: keep the kt+2 prefetches in flight ----
    if (kt + 2 < nkt)
      asm volatile("s_waitcnt vmcnt(4) lgkmcnt(0)\n\ts_barrier" ::: "memory");
    else if (kt + 1 < nkt)
      asm volatile("s_waitcnt vmcnt(0) lgkmcnt(0)\n\ts_barrier" ::: "memory");
    cbk = (cbk == 2) ? 0 : cbk + 1;
  }

  // ---- epilogue: cross-quad l reduce (deferred), then y stores ----
  {
    float lt0 = lq0 + __shfl_xor(lq0, 16, 64);
    lt0 += __shfl_xor(lt0, 32, 64);
    const float inv = 1.0f / lt0;
    const int qg = qw + l15;
    ushort_t* yp = y + ((size_t)(b * T_SEQ + qg)) * CEMB + h * HDIM + quad * 4;
#pragma unroll
    for (int nd = 0; nd < 4; nd++) {
      uint2 pk;
      pk.x = pkbf16(o2[nd][0] * inv, o2[nd][1] * inv);
      pk.y = pkbf16(o2[nd][2] * inv, o2[nd][3] * inv);
      *(uint2*)(yp + nd * 16) = pk;
    }
  }
}

// ---------- launcher ----------
extern "C" void kernel_launch(void* const* d_in, const int* in_sizes, int n_in,
                              void* d_out, int out_size, void* d_ws, size_t ws_size,
                              hipStream_t stream) {
  const float* x      = (const float*)d_in[0];  // [4,2048,768] fp32
  const float* w_attn = (const float*)d_in[1];  // [768,2304]
  const float* b_attn = (const float*)d_in[2];  // [2304]
  const float* w_proj = (const float*)d_in[3];  // [768,768]
  const float* b_proj = (const float*)d_in[4];  // [768]
  float* out = (float*)d_out;                   // [4,2048,768] fp32

  char* ws = (char*)d_ws;
  ushort_t* qkv = (ushort_t*)ws;                          // 8192*2304 bf16
  ushort_t* y   = qkv + (size_t)8192 * 2304;              // 8192*768
  ushort_t* xb  = y + (size_t)8192 * 768;                 // 8192*768 bf16 x
  ushort_t* wT  = xb + (size_t)8192 * 768;                // 2304*768 (w_attn^T)
  ushort_t* wpT = wT + (size_t)2304 * 768;                // 768*768  (w_proj^T)

  // fused prep: cvt x + transpose both weights
  prep_k<<<5376, 256, 0, stream>>>(x, xb, w_attn, wT, w_proj, wpT);

  // qkv = x @ w_attn + b_attn   (M=8192, N=2304, K=768), bf16 out
  // 1D grid 18*64=1152 (XCD-swizzled internally), NBX=18
  gemm_bt<false, 128><<<1152, 256, 0, stream>>>(xb, wT, b_attn, qkv, 8192, C3, CEMB, 18);

  // MFMA flash attention -> y [B,T,C] bf16; 64-q blocks, 256 thr, big-first
  attn_mfma_k<<<dim3(48, 32), 256, 0, stream>>>(qkv, y);

  // out = y @ w_proj + b_proj   (M=8192, N=768, K=768), fp32 out
  // 1D grid 6*128=768 (XCD-swizzled internally), NBX=6
  gemm_bt<true, 64><<<768, 256, 0, stream>>>(y, wpT, b_proj, out, 8192, CEMB, CEMB, 6);
}